// Round 2
// baseline (417.618 us; speedup 1.0000x reference)
//
#include <hip/hip_runtime.h>

#define NS    23      // columns per row (dose + 22 masks)
#define NSTR  22      // structures
#define ND    85      // dose bins in the loss
#define NB    256     // histogram bins
#define H     0.4f    // bin width (covers [0, 102.4))
#define INV_H 2.5f
#define EPSF  1.1920929e-07f
#define BLK   256

// ---------------- Pass 1: per-structure signed dose histogram ----------------
// +1 at bin(dose_true), -1 at bin(relu(dose_pred)) for every structure the
// sample belongs to; also count members per structure.
__global__ __launch_bounds__(BLK, 2) void dvh_hist_kernel(
    const float* __restrict__ yt,   // y_true  f32, N x 23
    const float* __restrict__ yp,   // y_pred  f32, N x 23 (only col 0 used)
    int N, int numTiles,
    int* __restrict__ g_hist,       // 22 x 256
    int* __restrict__ g_cnt)        // 22
{
    __shared__ int    shist[NSTR * NB];              // 22528 B
    __shared__ int    scnt[NSTR];
    __shared__ float4 stile4[(BLK * NS) / 4];        // 256 rows x 23 f32 = 23552 B
    float* st = (float*)stile4;

    const int tid = threadIdx.x;

    for (int i = tid; i < NSTR * NB; i += BLK) shist[i] = 0;
    if (tid < NSTR) scnt[tid] = 0;

    int cs[NSTR];
#pragma unroll
    for (int s = 0; s < NSTR; ++s) cs[s] = 0;

    const size_t totalF = (size_t)N * NS;

    for (int tile = blockIdx.x; tile < numTiles; tile += gridDim.x) {
        // ---- stage y_true tile (flat, coalesced 16B) ----
        size_t baseF = (size_t)tile * (BLK * NS);
        int cntF = (int)((totalF - baseF) < (size_t)(BLK * NS)
                             ? (totalF - baseF) : (size_t)(BLK * NS));
        int nv = cntF >> 2;   // full float4 chunks
        const float4* src = (const float4*)(yt + baseF);  // baseF*4 is 16B aligned
        for (int i = tid; i < nv; i += BLK) stile4[i] = src[i];
        for (int i = (nv << 2) + tid; i < cntF; i += BLK) st[i] = yt[baseF + i];
        __syncthreads();

        // ---- process rows ----
        int rows = cntF / NS;
        if (tid < rows) {
            const float* row = st + tid * NS;
            size_t n = (size_t)tile * BLK + tid;

            float t = row[0];
            int qt = (int)(t * INV_H);
            qt = qt > 0 ? qt : 0;
            qt = qt < (NB - 1) ? qt : (NB - 1);

            float p = yp[n * NS];          // col 0 gather, 92 B stride
            p = fmaxf(p, 0.0f);
            int qp = (int)(p * INV_H);
            qp = qp < (NB - 1) ? qp : (NB - 1);

            const unsigned int* rowu = (const unsigned int*)row;
#pragma unroll
            for (int s = 0; s < NSTR; ++s) {
                if (rowu[s + 1] != 0u) {   // mask != 0 (values are 0.0f / 1.0f)
                    atomicAdd(&shist[s * NB + qt], 1);
                    atomicAdd(&shist[s * NB + qp], -1);
                    cs[s]++;
                }
            }
        }
        __syncthreads();   // protect stile before next staging
    }

    // ---- flush block-local results ----
#pragma unroll
    for (int s = 0; s < NSTR; ++s)
        if (cs[s]) atomicAdd(&scnt[s], cs[s]);
    __syncthreads();

    for (int i = tid; i < NSTR * NB; i += BLK) {
        int v = shist[i];
        if (v) atomicAdd(&g_hist[i], v);
    }
    if (tid < NSTR) {
        int v = scnt[tid];
        if (v) atomicAdd(&g_cnt[tid], v);
    }
}

// ---------------- Pass 2: diff[s,d]^2 via histogram x sigmoid table ----------
__global__ void dvh_reduce_kernel(const int* __restrict__ g_hist,
                                  const int* __restrict__ g_cnt,
                                  float* __restrict__ dsq)   // ND x NSTR
{
    int d = blockIdx.x;        // 0..84
    int lane = threadIdx.x;    // 0..63

    float acc[NSTR];
#pragma unroll
    for (int s = 0; s < NSTR; ++s) acc[s] = 0.0f;

#pragma unroll
    for (int j = 0; j < NB / 64; ++j) {
        int q = lane + 64 * j;
        float c = ((float)q + 0.5f) * H;
        float x = c - (float)d;
        float w = 1.0f / (1.0f + __expf(-x));   // sigmoid(bin_center - d)
#pragma unroll
        for (int s = 0; s < NSTR; ++s)
            acc[s] += w * (float)g_hist[s * NB + q];
    }

#pragma unroll
    for (int s = 0; s < NSTR; ++s) {
#pragma unroll
        for (int o = 32; o; o >>= 1) acc[s] += __shfl_xor(acc[s], o);
    }

    if (lane == 0) {
#pragma unroll
        for (int s = 0; s < NSTR; ++s) {
            float diff = acc[s] / ((float)g_cnt[s] + EPSF);
            dsq[d * NSTR + s] = diff * diff;
        }
    }
}

// ---------------- Pass 3: per-structure L2 over d, sum, scale ---------------
__global__ void dvh_final_kernel(const float* __restrict__ dsq,
                                 float* __restrict__ out)
{
    int s = threadIdx.x;   // 0..63
    float r = 0.0f;
    if (s < NSTR) {
        float a = 0.0f;
        for (int d = 0; d < ND; ++d) a += dsq[d * NSTR + s];
        r = sqrtf(a);
    }
#pragma unroll
    for (int o = 32; o; o >>= 1) r += __shfl_xor(r, o);
    if (s == 0) out[0] = r / (float)(ND * NSTR);
}

extern "C" void kernel_launch(void* const* d_in, const int* in_sizes, int n_in,
                              void* d_out, int out_size, void* d_ws, size_t ws_size,
                              hipStream_t stream) {
    const float* yt = (const float*)d_in[0];
    const float* yp = (const float*)d_in[1];
    int N = in_sizes[0] / NS;

    int*   g_hist = (int*)d_ws;                                    // 22*256*4 = 22528 B
    int*   g_cnt  = (int*)((char*)d_ws + NSTR * NB * 4);           // 88 B
    float* dsq    = (float*)((char*)d_ws + NSTR * NB * 4 + 128);   // 85*22*4 B

    hipMemsetAsync(d_ws, 0, NSTR * NB * 4 + 128, stream);

    int numTiles = (N + BLK - 1) / BLK;
    int grid = numTiles < 512 ? numTiles : 512;

    dvh_hist_kernel<<<grid, BLK, 0, stream>>>(yt, yp, N, numTiles, g_hist, g_cnt);
    dvh_reduce_kernel<<<ND, 64, 0, stream>>>(g_hist, g_cnt, dsq);
    dvh_final_kernel<<<1, 64, 0, stream>>>(dsq, (float*)d_out);
}